// Round 1
// baseline (32.701 us; speedup 1.0000x reference)
//
#include <hip/hip_runtime.h>

// Spectrum integration: out[f] = sum_n w[n] * (2/sqrt(pi)) * c[n]^2 * arg * exp(-arg^2)
// where arg = (B_mean[n] - B_val[f]) * c[n], masked to |arg| <= 2.5.
//
// Refactor: d = B_mean - B_val;  contrib = s3 * d * exp2(-cl * d^2)
//   s3 = (2/sqrt(pi)) * w * c^3   (per line)
//   cl = c^2 * log2(e)            (per line)
// mask: |arg| <= 2.5  <=>  cl*d^2 <= 6.25*log2(e)

namespace {
constexpr float K_2_SQRT_PI = 1.1283791670955126f;  // 2/sqrt(pi)
constexpr float LOG2E       = 1.4426950408889634f;
constexpr float CUT_U       = 6.25f * 1.4426950408889634f;  // (2.5^2)*log2e
constexpr int CHUNK = 256;   // lines per block (staged in LDS)
constexpr int BLOCK = 1024;  // threads per block = fields covered per block
}

extern "C" __global__ void zero_out_kernel(float* __restrict__ out, int n) {
    int i = blockIdx.x * blockDim.x + threadIdx.x;
    if (i < n) out[i] = 0.0f;
}

extern "C" __global__ __launch_bounds__(BLOCK) void spectra_accum_kernel(
    const float* __restrict__ B_mean,
    const float* __restrict__ c_ext,
    const float* __restrict__ B_val,
    const float* __restrict__ weights,
    float* __restrict__ out,
    int n_lines, int n_fields)
{
    __shared__ float4 lds[CHUNK];
    const int tid  = threadIdx.x;
    const int base = blockIdx.x * CHUNK;

    // Stage this block's line chunk into LDS, precomputing per-line constants.
    if (tid < CHUNK) {
        const int n = base + tid;
        float bm = 0.0f, cc = 0.0f, ww = 0.0f;
        if (n < n_lines) {
            bm = B_mean[n];
            cc = c_ext[n];
            ww = weights[n];
        }
        const float c2 = cc * cc;
        // zero-padded lines give s3=0 -> contribute 0
        lds[tid] = make_float4(bm, c2 * LOG2E, K_2_SQRT_PI * ww * c2 * cc, 0.0f);
    }
    __syncthreads();

    const int f = blockIdx.y * BLOCK + tid;
    const float bv = (f < n_fields) ? B_val[f] : 0.0f;

    const int nl = min(CHUNK, n_lines - base);
    float acc = 0.0f;
#pragma unroll 4
    for (int i = 0; i < nl; ++i) {
        const float4 L = lds[i];            // broadcast ds_read_b128
        const float d  = L.x - bv;
        const float u  = L.y * (d * d);     // c^2*log2e*d^2 = arg^2*log2e
        const float e  = __builtin_amdgcn_exp2f(-u);  // exp(-arg^2)
        const float p  = (L.z * d) * e;
        acc += (u <= CUT_U) ? p : 0.0f;
    }

    if (f < n_fields) atomicAdd(&out[f], acc);
}

extern "C" void kernel_launch(void* const* d_in, const int* in_sizes, int n_in,
                              void* d_out, int out_size, void* d_ws, size_t ws_size,
                              hipStream_t stream) {
    const float* B_mean  = (const float*)d_in[0];
    const float* c_ext   = (const float*)d_in[1];
    const float* B_val   = (const float*)d_in[2];
    const float* weights = (const float*)d_in[3];
    float* out = (float*)d_out;

    const int n_lines  = in_sizes[0];
    const int n_fields = in_sizes[2];

    // d_out is poisoned by the harness; zero it every call (deterministic).
    zero_out_kernel<<<(out_size + 255) / 256, 256, 0, stream>>>(out, out_size);

    dim3 grid((n_lines + CHUNK - 1) / CHUNK, (n_fields + BLOCK - 1) / BLOCK);
    spectra_accum_kernel<<<grid, BLOCK, 0, stream>>>(
        B_mean, c_ext, B_val, weights, out, n_lines, n_fields);
}